// Round 1
// 133.630 us; speedup vs baseline: 1.0934x; 1.0934x over previous
//
#include <hip/hip_runtime.h>
#include <math.h>

#define B 64
#define S 512
#define E 128
#define NT 10
#define CHUNK_L 16      // stored steps per chunk (was 32)
#define WARM 64         // speculative warm-up steps; rho~0.83 -> 0.83^64 ~ 6.6e-6
#define NCHUNK (S / CHUNK_L)

// ---------------------------------------------------------------------------
// Quad rotation via DPP: lane j reads lane (j+d)&3 of its quad. 1 VALU op.
// rot1=0x39, rot2=0x4E, rot3=0x93.  (HW-verified rounds 7-13)
// Row rotation (16-lane rows): ror1=0x121 ror2=0x122 ror4=0x124, ror8=0x128 —
// only inside commutative reductions (direction-agnostic; HW-verified r12/13).
// RULE: cross-lane ops appear unconditionally under full exec; masks select
// on VALUES only. The only control flow in the loop is WAVE-UNIFORM
// (chunk-uniform t bounds / store predicate); the divergent l16<NT guard
// contains ONLY a store, no cross-lane ops.
// ---------------------------------------------------------------------------
template<int CTRL>
__device__ __forceinline__ float rotq(float x) {
    return __int_as_float(__builtin_amdgcn_mov_dpp(__float_as_int(x), CTRL, 0xF, 0xF, true));
}

__device__ __forceinline__ float frcp(float x) { return __builtin_amdgcn_rcpf(x); }

// tanh for |x| <= 2.08 (|cx| <= sig(1)*tanh(1)/(1-sig(1)) = 2.0704, provable):
// Pade [5/6], err <= 1e-6  (HW-verified rounds 11-13)
__device__ __forceinline__ float tanh_c(float x) {
    float s = x * x;
    float n = x * fmaf(s, fmaf(21.f, s, 1260.f), 10395.f);
    float d = fmaf(s, fmaf(s, s + 210.f, 4725.f), 10395.f);
    return n * frcp(d);
}

#define INV2PI 0.15915494309189535f

// ---------------------------------------------------------------------------
// k1: 16 positions/block; emb rows staged once into LDS (HW-verified r8-13).
// Wl/bl pre-scaled by 1/2pi -> Xproj in revolutions for raw v_cos_f32.
// UNCHANGED from the 144.3us kernel.
// ---------------------------------------------------------------------------
__global__ void __launch_bounds__(256) k1_xproj(
        const int* __restrict__ x, const float* __restrict__ emb,
        const float* __restrict__ Wf, const float* __restrict__ bf, const float* __restrict__ thf,
        const float* __restrict__ Wi, const float* __restrict__ bi, const float* __restrict__ thi,
        const float* __restrict__ Wu, const float* __restrict__ bu, const float* __restrict__ thu,
        const float* __restrict__ Wo, const float* __restrict__ bo, const float* __restrict__ tho,
        float* __restrict__ Xproj) {
    __shared__ __align__(16) float Wl[16][132];
    __shared__ __align__(16) float rows[16][132];
    __shared__ float bl[16];
    const int tid = threadIdx.x;
    {
        const float* Wm[4] = {Wf, Wi, Wu, Wo};
        for (int idx = tid; idx < 16 * E; idx += 256) {
            int e = idx >> 4, q = idx & 15;
            int g = q & 3, j = q >> 2;
            Wl[q][e] = Wm[g][e * 4 + j] * INV2PI;
        }
        if (tid < 16) {
            const float* bm[4] = {bf, bi, bu, bo};
            const float* tm[4] = {thf, thi, thu, tho};
            int g = tid & 3, j = tid >> 2;
            bl[tid] = (bm[g][j] + tm[g][j]) * INV2PI;
        }
    }
    const int p0 = blockIdx.x * 16;
    #pragma unroll
    for (int k = 0; k < 2; ++k) {
        int i4 = k * 256 + tid;              // float4 unit: 16 rows x 32
        int r  = i4 >> 5;
        int e4 = i4 & 31;
        const float4* rp = (const float4*)(emb + (size_t)x[p0 + r] * E);
        *(float4*)(&rows[r][e4 * 4]) = rp[e4];
    }
    __syncthreads();
    const int pl = tid >> 4, q = tid & 15;
    float acc = bl[q];
    #pragma unroll
    for (int e = 0; e < E; e += 4) {
        float4 wv = *(const float4*)(&Wl[q][e]);
        float4 rv = *(const float4*)(&rows[pl][e]);
        acc += rv.x * wv.x + rv.y * wv.y + rv.z * wv.z + rv.w * wv.w;
    }
    Xproj[(size_t)(p0 + pl) * 16 + q] = acc;
}

// ---------------------------------------------------------------------------
// k2 v6: chunked speculative scan WITH FUSED HEAD. Block = 4 batches x ONE
// chunk ci (wave-uniform bounds). Chunk stores steps [ci*L, ci*L+L); starts
// at ts = max(0, ci*L - WARM) from zero state: contraction (f <= 0.731,
// empirical rho ~0.83) kills the initial-state error to ~6.6e-6 within 64
// steps (-> ~3e-5 in logits, 3 orders below measured absmax). Chunks with
// c0 <= WARM start at t=0 -> bit-exact. Step body = round-13 VERBATIM.
//
// Head fusion: after the quad rotations, EVERY lane holds all four h values
// (hx0..hx3 = h_{(j+d)&3}). Lane l16 owns tag l16 (valid < NT=10):
//   lo = bt[tg] + sum_d hx_d * Wt[(j+d)&3][tg]        (4 fma)
// then log-softmax across the 16-lane row via commutative row_ror DPP
// butterflies (max, then sum of exp; padded lanes use -1e30 -> exp = 0).
// All off the recurrence chain. Writes `out` directly; hbuf/k3 deleted.
// ---------------------------------------------------------------------------
__global__ void __launch_bounds__(64) k2_recur(
        const float* __restrict__ Xproj,
        const float* __restrict__ Wf, const float* __restrict__ Wi,
        const float* __restrict__ Wu, const float* __restrict__ Wo,
        const float* __restrict__ Wt, const float* __restrict__ bt,
        float* __restrict__ out) {
    const int lane = threadIdx.x;
    const int ci = blockIdx.x >> 4;                      // chunk 0..NCHUNK-1
    const int b  = (blockIdx.x & 15) * 4 + (lane >> 4);  // batch
    const int l16 = lane & 15;
    const int g = l16 >> 2, j = l16 & 3;                 // gate, wire

    const int c0 = ci * CHUNK_L;                         // first stored step
    const int ts = (c0 > WARM) ? (c0 - WARM) : 0;        // start (wave-uniform)
    const int te = c0 + CHUNK_L;                         // end
    // (te - ts) in {16,32,48,64,80} -> always % P == 0

    // per-lane gate weight row (revolutions), pre-permuted: slot d = hx_{(j+d)&3}
    const float* Wg = (g == 0) ? Wf : (g == 1) ? Wi : (g == 2) ? Wu : Wo;
    const float w0 = Wg[(E + ((j + 0) & 3)) * 4 + j] * INV2PI;
    const float w1 = Wg[(E + ((j + 1) & 3)) * 4 + j] * INV2PI;
    const float w2 = Wg[(E + ((j + 2) & 3)) * 4 + j] * INV2PI;
    const float w3 = Wg[(E + ((j + 3) & 3)) * 4 + j] * INV2PI;

    // fused-head per-lane constants: tag tg = l16 (clamped for safe OOB loads;
    // lanes l16 >= NT are value-masked to -1e30 below)
    const int tg = (l16 < NT) ? l16 : (NT - 1);
    const float bt_l  = bt[tg];
    const float wt0h = Wt[(((j + 0) & 3)) * NT + tg];
    const float wt1h = Wt[(((j + 1) & 3)) * NT + tg];
    const float wt2h = Wt[(((j + 2) & 3)) * NT + tg];
    const float wt3h = Wt[(((j + 3) & 3)) * NT + tg];

    // z-product inclusion masks (wire j; HW-verified)
    const bool m_own = (j != 0);
    const bool m_r1  = (j == 0) || (j == 3);
    const bool m_r2  = (j != 1);
    // gate-combine masks (gate g; HW-verified round 12)
    const bool is_u  = (g == 2);
    const bool is_f  = (g == 0);
    const bool is_iu = (g == 1) || (g == 2);
    const bool is_o  = (g == 3);

    // unified rational-gate constants (u: tanh Pade[3/4]; else sigmoid form)
    const float b0 = is_u ? 0.f   : 0.5f;
    const float n0 = is_u ? 105.f : 26.25f;
    const float n1 = is_u ? 10.f  : 0.625f;
    const float d1 = is_u ? 45.f  : 11.25f;
    const float d2 = is_u ? 1.f   : 0.0625f;

    float hx0 = 0.f, hx1 = 0.f, hx2 = 0.f, hx3 = 0.f, cx = 0.f;

    const float* xp = Xproj + (size_t)b * S * 16 + (j * 4 + g);
    float* outb = out + ((size_t)b * S) * NT;

    constexpr int P = 8;                   // (te-ts) % P == 0 for all chunks
    float cur[P], nxt[P];
    #pragma unroll
    for (int p = 0; p < P; ++p) cur[p] = xp[(size_t)(ts + p) * 16];

    for (int tb = ts; tb < te; tb += P) {
        #pragma unroll
        for (int p = 0; p < P; ++p) {
            int tt = tb + P + p; if (tt >= te) tt = te - 1;   // clamped tail prefetch
            nxt[p] = xp[(size_t)tt * 16];
        }
        #pragma unroll
        for (int p = 0; p < P; ++p) {
            const int t = tb + p;

            float t1 = fmaf(w1, hx1, fmaf(w0, hx0, cur[p]));
            float t2 = fmaf(w3, hx3, w2 * hx2);
            float pre = t1 + t2;

            float c = __builtin_amdgcn_cosf(pre);   // v_cos_f32: cos(2*pi*pre)

            // z-product across wires (quads, verified)
            float a1 = rotq<0x39>(c), a2 = rotq<0x4E>(c), a3 = rotq<0x93>(c);
            float z = ((m_own ? c : 1.f) * (m_r1 ? a1 : 1.f)) * ((m_r2 ? a2 : 1.f) * a3);

            // unified rational gate
            float s = z * z;
            float num = z * fmaf(n1, s, n0);
            float den = fmaf(fmaf(d2, s, d1), s, 105.f);
            float y = fmaf(num, frcp(den), b0);

            // combine across gates: direction-agnostic butterfly products
            float ef  = is_f  ? y : 1.f;    // -> product over g-lanes = f
            float eiu = is_iu ? y : 1.f;    // -> i*u
            float eo  = is_o  ? y : 1.f;    // -> o
            float pf  = ef  * rotq<0x128>(ef);   pf  = pf  * rotq<0x124>(pf);
            float piu = eiu * rotq<0x128>(eiu);  piu = piu * rotq<0x124>(piu);
            float po  = eo  * rotq<0x128>(eo);   po  = po  * rotq<0x124>(po);

            cx = fmaf(pf, cx, piu);
            float h = po * tanh_c(cx);

            hx0 = h;
            hx1 = rotq<0x39>(h); hx2 = rotq<0x4E>(h); hx3 = rotq<0x93>(h);

            // ---- fused head (off the recurrence chain; wave-uniform guard) ----
            if (t >= c0) {
                float lo = fmaf(hx3, wt3h, fmaf(hx2, wt2h,
                           fmaf(hx1, wt1h, fmaf(hx0, wt0h, bt_l))));
                lo = (l16 < NT) ? lo : -1e30f;        // value mask, full exec
                float m = lo;                          // row-of-16 max butterfly
                m = fmaxf(m, rotq<0x121>(m));
                m = fmaxf(m, rotq<0x122>(m));
                m = fmaxf(m, rotq<0x124>(m));
                m = fmaxf(m, rotq<0x128>(m));
                float pe = __expf(lo - m);             // padded lanes -> 0
                float ssum = pe;                       // row-of-16 sum butterfly
                ssum += rotq<0x121>(ssum);
                ssum += rotq<0x122>(ssum);
                ssum += rotq<0x124>(ssum);
                ssum += rotq<0x128>(ssum);
                float lse = m + __logf(ssum);
                if (l16 < NT)                          // store-only divergence
                    outb[(size_t)t * NT + l16] = lo - lse;
            }
        }
        #pragma unroll
        for (int p = 0; p < P; ++p) cur[p] = nxt[p];
    }
}

extern "C" void kernel_launch(void* const* d_in, const int* in_sizes, int n_in,
                              void* d_out, int out_size, void* d_ws, size_t ws_size,
                              hipStream_t stream) {
    const int*   x   = (const int*)d_in[0];
    const float* emb = (const float*)d_in[1];
    const float* Wf  = (const float*)d_in[2];
    const float* bf  = (const float*)d_in[3];
    const float* thf = (const float*)d_in[4];
    const float* Wi  = (const float*)d_in[5];
    const float* bi  = (const float*)d_in[6];
    const float* thi = (const float*)d_in[7];
    const float* Wu  = (const float*)d_in[8];
    const float* bu  = (const float*)d_in[9];
    const float* thu = (const float*)d_in[10];
    const float* Wo  = (const float*)d_in[11];
    const float* bo  = (const float*)d_in[12];
    const float* tho = (const float*)d_in[13];
    const float* Wt  = (const float*)d_in[14];
    const float* bt  = (const float*)d_in[15];
    float* out = (float*)d_out;

    // workspace: Xproj [B*S*16] f32 only (hbuf eliminated)
    if (ws_size < (size_t)(B * S * 16) * sizeof(float)) return;
    float* Xproj = (float*)d_ws;

    k1_xproj<<<(B * S) / 16, 256, 0, stream>>>(x, emb, Wf, bf, thf, Wi, bi, thi,
                                               Wu, bu, thu, Wo, bo, tho, Xproj);
    k2_recur<<<NCHUNK * (B / 4), 64, 0, stream>>>(Xproj, Wf, Wi, Wu, Wo, Wt, bt, out);
}